// Round 7
// baseline (86.334 us; speedup 1.0000x reference)
//
#include <hip/hip_runtime.h>

#define NN 8192
#define DD 64
#define NL 3
#define LOG2E 1.4426950408889634f

typedef _Float16 f16x8 __attribute__((ext_vector_type(8)));
typedef _Float16 f16x2 __attribute__((ext_vector_type(2)));
typedef float f32x2 __attribute__((ext_vector_type(2)));
typedef float f32x16 __attribute__((ext_vector_type(16)));

union F16U { f16x8 v8; f16x2 h2[4]; };

// Prep kernel (unchanged math).
// Blocks [0,96): exp-domain tables:  a=(f1+ba)*log2e, b=f2*log2e
//   E1[l][i]=2^(a-4) f32, E1s[l][i]=2^(0.2a-4) f32 (row scale cancels exactly)
//   E2h[l][j]=2^b f16, E2sh[l][j]=2^(0.2b) f16
//   Identity: e_l = max(E1*E2h, E1s*E2sh)   (lrelu select == max, crossing c=0)
// Blocks [96,352): X -> fp16 in 32x32x16 B-fragment order.
__global__ __launch_bounds__(256) void mas_prep(const float* __restrict__ X,
                                                const float* __restrict__ Ws,
                                                const float* __restrict__ bWs,
                                                const float* __restrict__ a1,
                                                const float* __restrict__ a2,
                                                const float* __restrict__ ba,
                                                float* __restrict__ E1,
                                                float* __restrict__ E1s,
                                                _Float16* __restrict__ E2h,
                                                _Float16* __restrict__ E2sh,
                                                _Float16* __restrict__ Xf) {
    if (blockIdx.x < 96) {
        const int l = blockIdx.x >> 5;
        const int i = ((blockIdx.x & 31) << 8) + threadIdx.x;

        float xr[DD];
        const float4* X4 = (const float4*)(X + (size_t)i * DD);
#pragma unroll
        for (int q = 0; q < DD / 4; ++q) {
            float4 v = X4[q];
            xr[4 * q + 0] = v.x; xr[4 * q + 1] = v.y;
            xr[4 * q + 2] = v.z; xr[4 * q + 3] = v.w;
        }

        const float* W   = Ws  + l * DD * DD;
        const float* a1l = a1  + l * DD;
        const float* a2l = a2  + l * DD;
        const float* bwl = bWs + l * DD;

        float f1 = 0.f, f2 = 0.f;
#pragma unroll 4
        for (int d = 0; d < DD; ++d) {
            float wh = bwl[d];
            const float* wr = W + d * DD;
#pragma unroll
            for (int k = 0; k < DD; ++k) wh = fmaf(xr[k], wr[k], wh);
            f1 = fmaf(wh, a1l[d], f1);
            f2 = fmaf(wh, a2l[d], f2);
        }
        const float a = (f1 + ba[l]) * LOG2E;
        const float b = f2 * LOG2E;
        E1  [l * NN + i] = exp2f(a) * 0.0625f;
        E1s [l * NN + i] = exp2f(0.2f * a) * 0.0625f;
        E2h [l * NN + i] = (_Float16)exp2f(b);
        E2sh[l * NN + i] = (_Float16)exp2f(0.2f * b);
    } else {
        const int t = (blockIdx.x - 96) * 256 + threadIdx.x;   // 0..65535
        const int lane = t & 63;
        const int st = t >> 6;
        const int S = st >> 1, tl = st & 1;
        const int d = tl * 32 + (lane & 31);
        const int j0 = S * 16 + (lane >> 5) * 8;
        f16x8 v;
#pragma unroll
        for (int e = 0; e < 8; ++e) v[e] = (_Float16)X[(size_t)(j0 + e) * DD + d];
        *(f16x8*)(Xf + (size_t)t * 8) = v;
    }
}

// Main v6: each WAVE owns a 32-row tile x one j-split. Zero LDS, zero
// __syncthreads. w-gen in packed f16; z via f16 tree-add then f32 accumulate.
// C-fragments stored directly to numpart/out (layout verified on HW in R5).
__global__ __launch_bounds__(256, 4) void mas_main6(const _Float16* __restrict__ Xf,
                                                    const float* __restrict__ E1,
                                                    const float* __restrict__ E1s,
                                                    const _Float16* __restrict__ E2h,
                                                    const _Float16* __restrict__ E2sh,
                                                    float* __restrict__ numpart,
                                                    float* __restrict__ zpart,
                                                    float* __restrict__ out,
                                                    int nq) {
    const int tid  = threadIdx.x;
    const int lane = tid & 63;
    const int wv   = tid >> 6;
    const int hi   = lane >> 5;
    const int row  = lane & 31;
    const int i0   = blockIdx.x * 128 + wv * 32;   // wave-owned 32 rows
    const int i    = i0 + row;
    const int q    = blockIdx.y;

    const float e10f = E1[0 * NN + i], e11f = E1[1 * NN + i], e12f = E1[2 * NN + i];
    const float f10f = E1s[0 * NN + i], f11f = E1s[1 * NN + i], f12f = E1s[2 * NN + i];
    const f16x2 E10p = {(_Float16)e10f, (_Float16)e10f};
    const f16x2 E11p = {(_Float16)e11f, (_Float16)e11f};
    const f16x2 E12p = {(_Float16)e12f, (_Float16)e12f};
    const f16x2 F10p = {(_Float16)f10f, (_Float16)f10f};
    const f16x2 F11p = {(_Float16)f11f, (_Float16)f11f};
    const f16x2 F12p = {(_Float16)f12f, (_Float16)f12f};
    const f16x2 clampP = {(_Float16)60000.0f, (_Float16)60000.0f};

    const int jspan = NN / nq;          // per wave
    const int jbase = q * jspan;
    const int nst   = jspan >> 4;

    const _Float16* q20 = E2h  + 0 * NN + jbase + hi * 8;
    const _Float16* q21 = E2h  + 1 * NN + jbase + hi * 8;
    const _Float16* q22 = E2h  + 2 * NN + jbase + hi * 8;
    const _Float16* r20 = E2sh + 0 * NN + jbase + hi * 8;
    const _Float16* r21 = E2sh + 1 * NN + jbase + hi * 8;
    const _Float16* r22 = E2sh + 2 * NN + jbase + hi * 8;
    const f16x8* pB = (const f16x8*)Xf + (size_t)(jbase >> 4) * 128 + lane;

    f32x16 acc0 = {};
    f32x16 acc1 = {};
    f32x2 z0p = {0.f, 0.f}, z1p = {0.f, 0.f}, z2p = {0.f, 0.f};

    for (int s = 0; s < nst; ++s) {
        const int o = s * 16;
        F16U g0, g1, g2, h0, h1, h2v;
        g0.v8  = *(const f16x8*)(q20 + o);
        g1.v8  = *(const f16x8*)(q21 + o);
        g2.v8  = *(const f16x8*)(q22 + o);
        h0.v8  = *(const f16x8*)(r20 + o);
        h1.v8  = *(const f16x8*)(r21 + o);
        h2v.v8 = *(const f16x8*)(r22 + o);
        const f16x8 vb0 = pB[s * 128];
        const f16x8 vb1 = pB[s * 128 + 64];

        f16x2 e0[4], e1[4], e2[4];
#pragma unroll
        for (int g = 0; g < 4; ++g) {
            e0[g] = __builtin_elementwise_max(E10p * g0.h2[g], F10p * h0.h2[g]);
            e1[g] = __builtin_elementwise_max(E11p * g1.h2[g], F11p * h1.h2[g]);
            e2[g] = __builtin_elementwise_max(E12p * g2.h2[g], F12p * h2v.h2[g]);
        }
        // z: f16 tree (3 pk_add) then one f32 accumulate per layer
        const f16x2 t0 = (e0[0] + e0[1]) + (e0[2] + e0[3]);
        const f16x2 t1 = (e1[0] + e1[1]) + (e1[2] + e1[3]);
        const f16x2 t2 = (e2[0] + e2[1]) + (e2[2] + e2[3]);
        z0p += (f32x2){(float)t0[0], (float)t0[1]};
        z1p += (f32x2){(float)t1[0], (float)t1[1]};
        z2p += (f32x2){(float)t2[0], (float)t2[1]};

        F16U wa;
#pragma unroll
        for (int g = 0; g < 4; ++g)
            wa.h2[g] = __builtin_elementwise_min(e0[g] * e1[g] * e2[g], clampP);

        acc0 = __builtin_amdgcn_mfma_f32_32x32x16_f16(wa.v8, vb0, acc0, 0, 0, 0);
        acc1 = __builtin_amdgcn_mfma_f32_32x32x16_f16(wa.v8, vb1, acc1, 0, 0, 0);
    }

    float z0 = z0p[0] + z0p[1];
    float z1 = z1p[0] + z1p[1];
    float z2 = z2p[0] + z2p[1];
    // lanes (l, l+32) hold the same row with disjoint k-groups
    z0 += __shfl_xor(z0, 32);
    z1 += __shfl_xor(z1, 32);
    z2 += __shfl_xor(z2, 32);

    // Direct store of C-frags: C row = (e&3)+8*(e>>2)+4*hi, C col = lane&31.
    if (nq > 1) {
        float* np = numpart + (size_t)q * NN * DD;
#pragma unroll
        for (int e = 0; e < 16; ++e) {
            const int r = (e & 3) + 8 * (e >> 2) + 4 * hi;
            np[(size_t)(i0 + r) * DD + row]      = acc0[e];
            np[(size_t)(i0 + r) * DD + row + 32] = acc1[e];
        }
        if (lane < 32) {
            zpart[((size_t)q * 3 + 0) * NN + i] = z0;
            zpart[((size_t)q * 3 + 1) * NN + i] = z1;
            zpart[((size_t)q * 3 + 2) * NN + i] = z2;
        }
    } else {
        // single-split: full Z known in-wave; need per-output-row Z -> use
        // shfl to fetch row r's Z from lane r (both half-waves hold it).
#pragma unroll
        for (int e = 0; e < 16; ++e) {
            const int r = (e & 3) + 8 * (e >> 2) + 4 * hi;
            const float Z0 = __shfl(z0, r, 32);
            const float Z1 = __shfl(z1, r, 32);
            const float Z2 = __shfl(z2, r, 32);
            const float inv = 1.0f / (Z0 * (Z1 * Z2));
            out[(size_t)(i0 + r) * DD + row]      = acc0[e] * inv;
            out[(size_t)(i0 + r) * DD + row + 32] = acc1[e] * inv;
        }
    }
}

// Combine j-split partials (fixed order, deterministic). Scales cancel.
__global__ __launch_bounds__(256) void mas_comb6(const float* __restrict__ numpart,
                                                 const float* __restrict__ zpart,
                                                 float* __restrict__ out, int nq) {
    const int idx = blockIdx.x * 256 + threadIdx.x;
    const int i = idx >> 6;
    float s = 0.f;
    for (int q = 0; q < nq; ++q) s += numpart[(size_t)q * NN * DD + idx];
    float Z0 = 0.f, Z1 = 0.f, Z2 = 0.f;
    for (int q = 0; q < nq; ++q) {
        Z0 += zpart[((size_t)q * 3 + 0) * NN + i];
        Z1 += zpart[((size_t)q * 3 + 1) * NN + i];
        Z2 += zpart[((size_t)q * 3 + 2) * NN + i];
    }
    out[idx] = s / (Z0 * (Z1 * Z2));
}

extern "C" void kernel_launch(void* const* d_in, const int* in_sizes, int n_in,
                              void* d_out, int out_size, void* d_ws, size_t ws_size,
                              hipStream_t stream) {
    const float* X   = (const float*)d_in[0];
    // d_in[1] = A : unused by the reference computation (shape only)
    const float* Ws  = (const float*)d_in[2];
    const float* bWs = (const float*)d_in[3];
    const float* a1  = (const float*)d_in[4];
    const float* a2  = (const float*)d_in[5];
    const float* ba  = (const float*)d_in[6];
    float* out = (float*)d_out;

    float* E1  = (float*)d_ws;                   // [3][NN] f32
    float* E1s = E1 + NL * NN;                   // [3][NN] f32
    _Float16* E2h  = (_Float16*)(E1s + NL * NN); // [3][NN] f16
    _Float16* E2sh = E2h + NL * NN;              // [3][NN] f16
    _Float16* Xf   = E2sh + NL * NN;             // [NN*DD] f16 fragment order

    const size_t fixed = (size_t)(2 * NL * NN) * 4 + (size_t)(2 * NL * NN) * 2
                       + (size_t)NN * DD * 2;
    const size_t per_q = (size_t)NN * DD * 4 + (size_t)NL * NN * 4;
    int nq = 1;
    if (ws_size >= fixed + 16 * per_q) nq = 16;
    else if (ws_size >= fixed + 4 * per_q) nq = 4;

    float* numpart = (float*)(Xf + (size_t)NN * DD);  // [nq][NN][DD]
    float* zpart   = numpart + (size_t)nq * NN * DD;  // [nq][3][NN]

    mas_prep<<<352, 256, 0, stream>>>(X, Ws, bWs, a1, a2, ba, E1, E1s, E2h, E2sh, Xf);
    dim3 grid(NN / 128, nq);
    mas_main6<<<grid, 256, 0, stream>>>(Xf, E1, E1s, E2h, E2sh, numpart, zpart, out, nq);
    if (nq > 1)
        mas_comb6<<<NN * DD / 256, 256, 0, stream>>>(numpart, zpart, out, nq);
}